// Round 2
// baseline (48.246 us; speedup 1.0000x reference)
//
#include <hip/hip_runtime.h>

#define EPSV 1e-4f

// One cyclic-Jacobi rotation for the symmetric 3x3, pair (p,q), other index r.
__device__ __forceinline__ void jrot(float& app, float& aqq, float& apq,
                                     float& arp, float& arq,
                                     float& vap, float& vaq,
                                     float& vbp, float& vbq,
                                     float& vcp, float& vcq) {
  const float apq0 = apq;
  float tau = (aqq - app) / (2.0f * apq0);               // may be inf/nan if apq0==0
  float t = copysignf(1.0f / (fabsf(tau) + sqrtf(fmaf(tau, tau, 1.0f))), tau);
  if (apq0 == 0.0f) t = 0.0f;                            // covers the nan case too
  const float c = rsqrtf(fmaf(t, t, 1.0f));
  const float s = t * c;
  const float d = t * apq0;
  app -= d; aqq += d; apq = 0.0f;
  const float rp = arp, rq = arq;
  arp = c * rp - s * rq;
  arq = s * rp + c * rq;
  float x, y;
  x = vap; y = vaq; vap = c * x - s * y; vaq = s * x + c * y;
  x = vbp; y = vbq; vbp = c * x - s * y; vbq = s * x + c * y;
  x = vcp; y = vcq; vcp = c * x - s * y; vcq = s * x + c * y;
}

__global__ __launch_bounds__(256) void spd_decoder_kernel(
    const float* __restrict__ vech, const float* __restrict__ W1,
    const float* __restrict__ W2, const float* __restrict__ W3,
    float* __restrict__ out, int B) {
  __shared__ float Tsh[21];                 // W2@W1 (7x3)
  __shared__ float Msh[27];                 // W3@W2@W1 (9x3)
  __shared__ __align__(16) float buf[4][2592];  // per-wave staging (32 elem * 81)

  const int tid = threadIdx.x;

  // ---- per-block precompute of M = W3@W2@W1 ----
  if (tid < 21) {
    const int r = tid / 3, c = tid % 3;
    float acc = 0.f;
#pragma unroll
    for (int j = 0; j < 5; ++j) acc += W2[r * 5 + j] * W1[j * 3 + c];
    Tsh[tid] = acc;
  }
  __syncthreads();
  if (tid < 27) {
    const int r = tid / 3, c = tid % 3;
    float acc = 0.f;
#pragma unroll
    for (int j = 0; j < 7; ++j) acc += W3[r * 7 + j] * Tsh[j * 3 + c];
    Msh[tid] = acc;
  }
  __syncthreads();  // the ONLY block-wide barrier after this point: none.

  float M[27];
#pragma unroll
  for (int i = 0; i < 27; ++i) M[i] = Msh[i];

  // ---- load vech, build symmetric 3x3 ----
  const int e = blockIdx.x * 256 + tid;     // B is a multiple of 256
  const float2* vp = reinterpret_cast<const float2*>(vech + (size_t)e * 6);
  const float2 p0 = vp[0], p1 = vp[1], p2 = vp[2];
  float a00 = p0.x, a01 = p0.y, a02 = p1.x, a11 = p1.y, a12 = p2.x, a22 = p2.y;

  // ---- 3x3 Jacobi eigendecomposition, V accumulated ----
  float v00 = 1.f, v01 = 0.f, v02 = 0.f;
  float v10 = 0.f, v11 = 1.f, v12 = 0.f;
  float v20 = 0.f, v21 = 0.f, v22 = 1.f;
#pragma unroll
  for (int sweep = 0; sweep < 5; ++sweep) {
    jrot(a00, a11, a01, a02, a12, v00, v01, v10, v11, v20, v21);  // (0,1), r=2
    jrot(a00, a22, a02, a01, a12, v00, v02, v10, v12, v20, v22);  // (0,2), r=1
    jrot(a11, a22, a12, a01, a02, v01, v02, v11, v12, v21, v22);  // (1,2), r=0
  }

  const float e0 = expf(a00) - EPSV;
  const float e1 = expf(a11) - EPSV;
  const float e2 = expf(a22) - EPSV;

  // ---- out = sum_k e_k * (M v_k)(M v_k)^T + eps*I, symmetric upper (45) ----
  float o[45];
#pragma unroll
  for (int i = 0; i < 45; ++i) o[i] = 0.f;

#define ACCUM_COL(vk0, vk1, vk2, ek)                                   \
  {                                                                    \
    float g[9];                                                        \
    _Pragma("unroll") for (int i = 0; i < 9; ++i)                      \
        g[i] = fmaf(M[i * 3 + 0], (vk0),                               \
                    fmaf(M[i * 3 + 1], (vk1), M[i * 3 + 2] * (vk2)));  \
    int idx = 0;                                                       \
    _Pragma("unroll") for (int i = 0; i < 9; ++i) {                    \
      const float sgi = (ek)*g[i];                                     \
      _Pragma("unroll") for (int j = i; j < 9; ++j) {                  \
        o[idx] = fmaf(sgi, g[j], o[idx]);                              \
        ++idx;                                                         \
      }                                                                \
    }                                                                  \
  }

  ACCUM_COL(v00, v10, v20, e0);
  ACCUM_COL(v01, v11, v21, e1);
  ACCUM_COL(v02, v12, v22, e2);
#undef ACCUM_COL

  {  // diagonal += eps
    int idx = 0;
#pragma unroll
    for (int i = 0; i < 9; ++i) {
      o[idx] += EPSV;
      idx += 9 - i;
    }
  }

  // ---- wave-private staged store, two phases of 32 elements, NO block
  // barrier and NO vmcnt drain: each wave only touches buf[w]; within a
  // wave DS ops execute in order, so wave-local lgkmcnt(0) + compiler
  // fence covers the cross-lane RAW (write->read) and WAR (read->next
  // write) hazards while global stores stay in flight. ----
  const int w = tid >> 6, l = tid & 63;
  float* wbuf = &buf[w][0];
  const size_t base = (size_t)(blockIdx.x * 256 + w * 64) * 81;

#pragma unroll
  for (int h = 0; h < 2; ++h) {
    if ((l >> 5) == h) {
      const int ll = l & 31;
      float* dst = wbuf + ll * 81;  // stride 81 (mod 32 = 17): conflict-free
#pragma unroll
      for (int i = 0; i < 9; ++i) {
#pragma unroll
        for (int j = 0; j < 9; ++j) {
          const int ii = i < j ? i : j;
          const int jj = i < j ? j : i;
          dst[i * 9 + j] = o[ii * 9 - ii * (ii - 1) / 2 + (jj - ii)];
        }
      }
    }
    // writes landed before any lane's reads (wave-local wait, no vmcnt)
    asm volatile("s_waitcnt lgkmcnt(0)" ::: "memory");

    const size_t sb = base + (size_t)h * 2592;
    const float4* rbuf = reinterpret_cast<const float4*>(wbuf);
    float4* outv = reinterpret_cast<float4*>(out + sb);
#pragma unroll
    for (int it = 0; it < 10; ++it) outv[it * 64 + l] = rbuf[it * 64 + l];
    if (l < 8) outv[640 + l] = rbuf[640 + l];  // 648 float4 total

    // reads landed (data in VGPRs) before next phase overwrites the buffer
    asm volatile("s_waitcnt lgkmcnt(0)" ::: "memory");
  }
}

extern "C" void kernel_launch(void* const* d_in, const int* in_sizes, int n_in,
                              void* d_out, int out_size, void* d_ws, size_t ws_size,
                              hipStream_t stream) {
  const float* vech = (const float*)d_in[0];
  const float* W1 = (const float*)d_in[1];
  const float* W2 = (const float*)d_in[2];
  const float* W3 = (const float*)d_in[3];
  float* out = (float*)d_out;
  const int B = in_sizes[0] / 6;  // 262144
  dim3 grid(B / 256), block(256);
  hipLaunchKernelGGL(spd_decoder_kernel, grid, block, 0, stream,
                     vech, W1, W2, W3, out, B);
}

// Round 3
// 24.348 us; speedup vs baseline: 1.9815x; 1.9815x over previous
//
#include <hip/hip_runtime.h>

#define EPSV 1e-4f

// One cyclic-Jacobi rotation for the symmetric 3x3, pair (p,q), other index r.
__device__ __forceinline__ void jrot(float& app, float& aqq, float& apq,
                                     float& arp, float& arq,
                                     float& vap, float& vaq,
                                     float& vbp, float& vbq,
                                     float& vcp, float& vcq) {
  const float apq0 = apq;
  float tau = (aqq - app) / (2.0f * apq0);               // may be inf/nan if apq0==0
  float t = copysignf(1.0f / (fabsf(tau) + sqrtf(fmaf(tau, tau, 1.0f))), tau);
  if (apq0 == 0.0f) t = 0.0f;                            // covers the nan case too
  const float c = rsqrtf(fmaf(t, t, 1.0f));
  const float s = t * c;
  const float d = t * apq0;
  app -= d; aqq += d; apq = 0.0f;
  const float rp = arp, rq = arq;
  arp = c * rp - s * rq;
  arq = s * rp + c * rq;
  float x, y;
  x = vap; y = vaq; vap = c * x - s * y; vaq = s * x + c * y;
  x = vbp; y = vbq; vbp = c * x - s * y; vbq = s * x + c * y;
  x = vcp; y = vcq; vcp = c * x - s * y; vcq = s * x + c * y;
}

// min-2-waves/SIMD: caps the allocator at 256 VGPR so it cannot chase an
// 8-wave/SIMD 64-reg target and spill (round-2 regression: VGPR=68 < ~90
// live values -> scratch traffic doubled HBM writes). LDS (41.5KB -> 3
// blocks/CU = 12 waves/CU) is the binding occupancy limit regardless.
__global__ __launch_bounds__(256, 2) void spd_decoder_kernel(
    const float* __restrict__ vech, const float* __restrict__ W1,
    const float* __restrict__ W2, const float* __restrict__ W3,
    float* __restrict__ out, int B) {
  __shared__ float Tsh[21];                 // W2@W1 (7x3)
  __shared__ float Msh[27];                 // W3@W2@W1 (9x3)
  __shared__ __align__(16) float buf[4][2592];  // per-wave staging (32 elem * 81)

  const int tid = threadIdx.x;

  // ---- per-block precompute of M = W3@W2@W1 ----
  if (tid < 21) {
    const int r = tid / 3, c = tid % 3;
    float acc = 0.f;
#pragma unroll
    for (int j = 0; j < 5; ++j) acc += W2[r * 5 + j] * W1[j * 3 + c];
    Tsh[tid] = acc;
  }
  __syncthreads();
  if (tid < 27) {
    const int r = tid / 3, c = tid % 3;
    float acc = 0.f;
#pragma unroll
    for (int j = 0; j < 7; ++j) acc += W3[r * 7 + j] * Tsh[j * 3 + c];
    Msh[tid] = acc;
  }
  __syncthreads();

  // ---- load vech, build symmetric 3x3 ----
  const int e = blockIdx.x * 256 + tid;     // B is a multiple of 256
  const float2* vp = reinterpret_cast<const float2*>(vech + (size_t)e * 6);
  const float2 p0 = vp[0], p1 = vp[1], p2 = vp[2];
  float a00 = p0.x, a01 = p0.y, a02 = p1.x, a11 = p1.y, a12 = p2.x, a22 = p2.y;

  // ---- 3x3 Jacobi eigendecomposition, V accumulated ----
  float v00 = 1.f, v01 = 0.f, v02 = 0.f;
  float v10 = 0.f, v11 = 1.f, v12 = 0.f;
  float v20 = 0.f, v21 = 0.f, v22 = 1.f;
#pragma unroll
  for (int sweep = 0; sweep < 5; ++sweep) {
    jrot(a00, a11, a01, a02, a12, v00, v01, v10, v11, v20, v21);  // (0,1), r=2
    jrot(a00, a22, a02, a01, a12, v00, v02, v10, v12, v20, v22);  // (0,2), r=1
    jrot(a11, a22, a12, a01, a02, v01, v02, v11, v12, v21, v22);  // (1,2), r=0
  }

  const float e0 = expf(a00) - EPSV;
  const float e1 = expf(a11) - EPSV;
  const float e2 = expf(a22) - EPSV;

  // ---- g_k = M v_k (9 floats each); M read from LDS and immediately dead.
  // Output values are generated ON THE FLY from g0,g1,g2,e* in the store
  // phase: out[i][j] = e0 g0i g0j + e1 g1i g1j + e2 g2i g2j + eps*delta_ij.
  // Peak live set ~50 regs (was ~90 with o[45]) -> no spill possible. ----
  float g0[9], g1[9], g2[9];
#pragma unroll
  for (int i = 0; i < 9; ++i) {
    const float m0 = Msh[i * 3 + 0], m1 = Msh[i * 3 + 1], m2 = Msh[i * 3 + 2];
    g0[i] = fmaf(m0, v00, fmaf(m1, v10, m2 * v20));
    g1[i] = fmaf(m0, v01, fmaf(m1, v11, m2 * v21));
    g2[i] = fmaf(m0, v02, fmaf(m1, v12, m2 * v22));
  }

  // ---- wave-private staged store, two phases of 32 elements, no block
  // barrier and no vmcnt drain: each wave only touches buf[w]; DS ops
  // complete in order within a wave, so wave-local lgkmcnt(0) covers the
  // cross-lane RAW (write->read) and WAR (read->next write) hazards while
  // global stores stay in flight across phases and waves. ----
  const int w = tid >> 6, l = tid & 63;
  float* wbuf = &buf[w][0];
  const size_t base = (size_t)(blockIdx.x * 256 + w * 64) * 81;

#pragma unroll
  for (int h = 0; h < 2; ++h) {
    if ((l >> 5) == h) {
      const int ll = l & 31;
      float* dst = wbuf + ll * 81;  // stride 81 (mod 32 = 17): conflict-free
#pragma unroll
      for (int i = 0; i < 9; ++i) {
        const float t0 = e0 * g0[i], t1 = e1 * g1[i], t2 = e2 * g2[i];
#pragma unroll
        for (int j = 0; j < 9; ++j) {
          float val = fmaf(t0, g0[j], fmaf(t1, g1[j], t2 * g2[j]));
          if (i == j) val += EPSV;     // compile-time branch after unroll
          dst[i * 9 + j] = val;
        }
      }
    }
    // writes landed before any lane's reads (wave-local wait, no vmcnt)
    asm volatile("s_waitcnt lgkmcnt(0)" ::: "memory");
    __builtin_amdgcn_sched_barrier(0);

    const size_t sb = base + (size_t)h * 2592;
    const float4* rbuf = reinterpret_cast<const float4*>(wbuf);
    float4* outv = reinterpret_cast<float4*>(out + sb);
#pragma unroll
    for (int it = 0; it < 10; ++it) outv[it * 64 + l] = rbuf[it * 64 + l];
    if (l < 8) outv[640 + l] = rbuf[640 + l];  // 648 float4 total

    // reads landed (data in VGPRs) before next phase overwrites the buffer
    asm volatile("s_waitcnt lgkmcnt(0)" ::: "memory");
    __builtin_amdgcn_sched_barrier(0);
  }
}

extern "C" void kernel_launch(void* const* d_in, const int* in_sizes, int n_in,
                              void* d_out, int out_size, void* d_ws, size_t ws_size,
                              hipStream_t stream) {
  const float* vech = (const float*)d_in[0];
  const float* W1 = (const float*)d_in[1];
  const float* W2 = (const float*)d_in[2];
  const float* W3 = (const float*)d_in[3];
  float* out = (float*)d_out;
  const int B = in_sizes[0] / 6;  // 262144
  dim3 grid(B / 256), block(256);
  hipLaunchKernelGGL(spd_decoder_kernel, grid, block, 0, stream,
                     vech, W1, W2, W3, out, B);
}